// Round 12
// baseline (26.457 us; speedup 1.0000x reference)
//
#include <hip/hip_runtime.h>

typedef float f32x4 __attribute__((ext_vector_type(4)));

#define BB 128
#define HH 256
#define WW 256
#define TILE_J 16
#define NTHREADS 256
#define JTILES (WW / TILE_J)      // 16
#define NBLOCKS (BB * JTILES)     // 2048
#define NTOT ((double)((size_t)BB * WW * WW))

// Reachable bins for u in [0.0235, 1): rint(50u+110) in [111,160].
// 56-wide, 16B-aligned window [108,164); outside is provably zero.
#define BIN0 108
#define BINW 56
#define BINP 56                   // 224 B rows, 16B-aligned
#define NV4  (BINW / 4)           // 14 float4 per row
#define NLOSS (TILE_J * NV4)      // 224 float4s per side per block

// Full compiler memory fence: loads cannot be hoisted/sunk across.
#define MEMFENCE() asm volatile("" ::: "memory")

__global__ __launch_bounds__(NTHREADS, 8)
void scatter_loss_kernel(const float* __restrict__ up,
                         const float* __restrict__ left,
                         const float* __restrict__ right,
                         double* __restrict__ partial) {
    __shared__ __align__(16) int   bins[2][TILE_J][BINP];   // 7168 B, float bits
    __shared__ __align__(16) float stage[2][TILE_J][BINP];  // 7168 B, l/r windows

    const int bid = blockIdx.x;
    const int k  = bid & 127;        // batch; all 16 j-tiles of k on one XCD
    const int jt = bid >> 7;         // 0..15
    const int j0 = jt * TILE_J;
    const int tid = threadIdx.x;

    const int q = tid & 3;           // float4 within the 16-col row
    const int r = tid >> 2;          // 0..63
    const f32x4* up4 = (const f32x4*)(up + (size_t)k * (HH * WW));
    const int col4 = (j0 >> 2) + q;

    // ---- depth-2 pipeline: issue u0,u1 only ----
    f32x4 u0 = up4[(r +   0) * (WW / 4) + col4];
    f32x4 u1 = up4[(r +  64) * (WW / 4) + col4];

    // zero bins: 2*16*56 = 1792 ints, 7 per thread (overlaps u0/u1 latency)
    #pragma unroll
    for (int e = tid; e < 2 * TILE_J * BINP; e += NTHREADS)
        (&bins[0][0][0])[e] = 0;

    MEMFENCE();                       // u2 issue stays HERE (not hoisted)
    f32x4 u2 = up4[(r + 128) * (WW / 4) + col4];
    MEMFENCE();

    // barrier 1: LDS-only drain + raw barrier (bins zeroed); VMEM in flight.
    asm volatile("s_waitcnt lgkmcnt(0)" ::: "memory");
    __builtin_amdgcn_s_barrier();

    #define SCATTER_S(UV, S)                                                  \
    {                                                                         \
        const int i = r + 64 * (S);                                           \
        const int sidesel = (i > 128) ? 1 : 0;                                \
        const int ad = sidesel ? (i - 128) : (128 - i); /* i==128 -> no-op */ \
        const float v = __fdiv_rn((float)ad, 60.0f);                          \
        const int vbits = __float_as_int(v);                                  \
        int* srow = &bins[sidesel][q * 4][0];                                 \
        _Pragma("unroll")                                                     \
        for (int c = 0; c < 4; ++c) {                                         \
            const float uval = (UV)[c];                                       \
            if (uval >= 0.0235f) {                                            \
                /* clip(rint(u*50+110),0,255); no FMA contraction; */         \
                /* rintf = round-half-even = np.round.             */         \
                const float t = __fadd_rn(__fmul_rn(uval, 50.0f), 110.0f);    \
                int bin = (int)rintf(t);                                      \
                int bw = min(max(bin - BIN0, 0), BINW - 1);                   \
                atomicMax(srow + c * BINP + bw, vbits);                       \
            }                                                                 \
        }                                                                     \
    }

    // ---- stage 0: wait u0, scatter; consumption paces issue ----
    asm volatile("" : "+v"(u0));      // forces counted vmcnt wait for u0 only
    SCATTER_S(u0, 0)

    // issue u3 + window DMAs now (arrive during s1..s3 / loss barrier)
    MEMFENCE();
    f32x4 u3 = up4[(r + 192) * (WW / 4) + col4];
    const int lrow = tid / NV4;
    const int lc4  = tid - lrow * NV4;
    if (tid < NLOSS) {
        const size_t goff = (size_t)k * (HH * WW) + (size_t)(j0 + lrow) * WW
                          + BIN0 + (size_t)lc4 * 4;
        const int wv = tid >> 6;
        char* sbase = (char*)(&stage[0][0][0]);
        __builtin_amdgcn_global_load_lds(
            (const __attribute__((address_space(1))) void*)(left + goff),
            (__attribute__((address_space(3))) void*)(sbase + wv * 1024),
            16, 0, 0);
        __builtin_amdgcn_global_load_lds(
            (const __attribute__((address_space(1))) void*)(right + goff),
            (__attribute__((address_space(3))) void*)(sbase + 3584 + wv * 1024),
            16, 0, 0);
    }
    MEMFENCE();

    // ---- stage 1..3 ----
    asm volatile("" : "+v"(u1));
    SCATTER_S(u1, 1)
    asm volatile("" : "+v"(u2));
    SCATTER_S(u2, 2)
    asm volatile("" : "+v"(u3));
    SCATTER_S(u3, 3)
    #undef SCATTER_S

    // barrier 2: full __syncthreads -> drains vmcnt(0); staged left/right
    // windows guaranteed landed in LDS.
    __syncthreads();

    // ---- loss phase: everything from LDS, no global stalls ----
    double lsum = 0.0;
    if (tid < NLOSS) {
        const int4 a = *(const int4*)&bins[0][lrow][lc4 * 4];
        const int4 b = *(const int4*)&bins[1][lrow][lc4 * 4];
        const float4 lv = *(const float4*)&stage[0][lrow][lc4 * 4];
        const float4 rv = *(const float4*)&stage[1][lrow][lc4 * 4];
        const int* ai = (const int*)&a;
        const int* bi = (const int*)&b;
        const float* lf = (const float*)&lv;
        const float* rf = (const float*)&rv;
        #pragma unroll
        for (int c = 0; c < 4; ++c) {
            const float fl = __int_as_float(ai[c]);
            const float fr = __int_as_float(bi[c]);
            if (fl != 0.0f) {
                const float d = fabsf(__fsub_rn(fl, lf[c]));
                if (d < 0.2f) lsum += (double)d;
            }
            if (fr != 0.0f) {
                const float d = fabsf(__fsub_rn(fr, rf[c]));
                if (d < 0.2f) lsum += (double)d;
            }
        }
    }

    // block reduction (double): wave shfl then cross-wave via LDS
    #pragma unroll
    for (int off = 32; off > 0; off >>= 1)
        lsum += __shfl_down(lsum, off, 64);
    __shared__ double wsum[NTHREADS / 64];
    if ((tid & 63) == 0) wsum[tid >> 6] = lsum;
    __syncthreads();
    if (tid == 0) {
        double t = 0.0;
        #pragma unroll
        for (int w2 = 0; w2 < NTHREADS / 64; ++w2) t += wsum[w2];
        partial[bid] = t;   // plain store, written every call
    }
}

__global__ __launch_bounds__(NTHREADS)
void finalize_kernel(const double* __restrict__ partial, float* __restrict__ out) {
    double s = 0.0;
    for (int e = threadIdx.x; e < NBLOCKS; e += NTHREADS) s += partial[e];
    #pragma unroll
    for (int off = 32; off > 0; off >>= 1)
        s += __shfl_down(s, off, 64);
    __shared__ double sh[NTHREADS / 64];
    if ((threadIdx.x & 63) == 0) sh[threadIdx.x >> 6] = s;
    __syncthreads();
    if (threadIdx.x == 0) {
        double t = 0.0;
        #pragma unroll
        for (int w2 = 0; w2 < NTHREADS / 64; ++w2) t += sh[w2];
        out[0] = (float)(t / NTOT);
    }
}

extern "C" void kernel_launch(void* const* d_in, const int* in_sizes, int n_in,
                              void* d_out, int out_size, void* d_ws, size_t ws_size,
                              hipStream_t stream) {
    const float* up    = (const float*)d_in[0];
    const float* left  = (const float*)d_in[1];
    const float* right = (const float*)d_in[2];
    float* out = (float*)d_out;
    double* partial = (double*)d_ws;   // NBLOCKS doubles = 16 KB

    // INSTRUMENTATION ROUND: scatter launched twice (idempotent — same
    // partial[] written both times; output unchanged). Pass 1 = L3-cold
    // (harness fills evict between replays), pass 2 = L3-hot.
    //   dur - 17.34us  =  S_hot + gap.
    // S_hot << S_cold  -> pass 1 is HBM-delivery-bound (pursue delivery).
    // S_hot ~= S_cold  -> kernel internally bound (pursue atomic/VALU path).
    scatter_loss_kernel<<<dim3(NBLOCKS), dim3(NTHREADS), 0, stream>>>(
        up, left, right, partial);
    scatter_loss_kernel<<<dim3(NBLOCKS), dim3(NTHREADS), 0, stream>>>(
        up, left, right, partial);
    finalize_kernel<<<dim3(1), dim3(NTHREADS), 0, stream>>>(partial, out);
}

// Round 13
// 19.152 us; speedup vs baseline: 1.3814x; 1.3814x over previous
//
#include <hip/hip_runtime.h>

typedef float f32x4 __attribute__((ext_vector_type(4)));

#define BB 128
#define HH 256
#define WW 256
#define TILE_J 16
#define NTHREADS 256
#define NUNITS 4096               // (k 128) x (jt 16) x (ihalf 2), one per WAVE
#define NBLOCKS (NUNITS / 4)      // 1024 blocks x 4 waves
#define NTOT ((double)((size_t)BB * WW * WW))

// Reachable bins for u in [0.0235, 1): rint(50u+110) in [111,160].
// 56-wide, 16B-aligned window [108,164); outside is provably zero.
#define BIN0 108
#define BINW 56
#define BINP 56                   // 224 B rows, 16B-aligned
#define NV4  (BINW / 4)           // 14 float4 per row

#define MEMFENCE() asm volatile("" ::: "memory")

__global__ __launch_bounds__(NTHREADS, 4)
void scatter_loss_kernel(const float* __restrict__ up,
                         const float* __restrict__ left,
                         const float* __restrict__ right,
                         double* __restrict__ partial) {
    // One wave = one unit (k, jt, ihalf); bins slice is wave-PRIVATE ->
    // no inter-wave sync: ZERO barriers in this kernel. Convoy-breaker.
    __shared__ __align__(16) int bins[4][TILE_J][BINP];   // 14336 B

    const int tid  = threadIdx.x;
    const int wid  = tid >> 6;
    const int lane = tid & 63;
    const int gid  = blockIdx.x * 4 + wid;     // 0..4095
    const int k    = gid & 127;                // inner: round-10 swizzle
    const int g2   = gid >> 7;                 // 0..31
    const int ihalf = g2 & 1;                  // 0: i in [0,128] left; 1: [128,256) right
    const int jt   = g2 >> 1;                  // 0..15
    const int j0   = jt * TILE_J;
    const int i0   = ihalf << 7;

    const int q = lane & 3;          // float4 within the 16-col row
    const int r = lane >> 2;         // 0..15
    const f32x4* up4 = (const f32x4*)(up + (size_t)k * (HH * WW));
    const int col4 = (j0 >> 2) + q;
    // stage s covers rows i = i0 + 16*s + r, s = 0..7

    // ---- depth-2 per-wave pipeline: issue s=0,1 ----
    f32x4 uA = up4[(i0 +  0 + r) * (WW / 4) + col4];
    f32x4 uB = up4[(i0 + 16 + r) * (WW / 4) + col4];

    // zero own bins slice: 896 ints = 224 int4; lanes cover e, e+64, e+128, e+192
    int* mybins = &bins[wid][0][0];
    int4* mb4 = (int4*)mybins;
    const int4 z4 = {0, 0, 0, 0};
    mb4[lane] = z4;
    mb4[lane + 64] = z4;
    mb4[lane + 128] = z4;
    if (lane < 32) mb4[lane + 192] = z4;
    asm volatile("s_waitcnt lgkmcnt(0)" ::: "memory");   // own-wave only; no barrier

    // i==128 (ihalf=1,s=0,r=0): ad=0 -> v=0 -> atomicMax no-op, matches ref.
    #define STAGE(UREG, S)                                                    \
    {                                                                         \
        asm volatile("" : "+v"(UREG));  /* counted vmcnt wait for UREG */     \
        const int i = i0 + 16 * (S) + r;                                      \
        const int ad = ihalf ? (i - 128) : (128 - i);                         \
        const float v = __fdiv_rn((float)ad, 60.0f);                          \
        const int vbits = __float_as_int(v);                                  \
        _Pragma("unroll")                                                     \
        for (int c = 0; c < 4; ++c) {                                         \
            const float uval = (UREG)[c];                                     \
            if (uval >= 0.0235f) {                                            \
                /* clip(rint(u*50+110),0,255); no FMA contraction; */         \
                /* rintf = round-half-even = np.round.             */         \
                const float t = __fadd_rn(__fmul_rn(uval, 50.0f), 110.0f);    \
                int bin = (int)rintf(t);                                      \
                int bw = min(max(bin - BIN0, 0), BINW - 1);                   \
                atomicMax(mybins + (q * 4 + c) * BINP + bw, vbits);           \
            }                                                                 \
        }                                                                     \
    }

    // paced: consume stage s, then issue stage s+2 (MEMFENCE pins issue point)
    STAGE(uA, 0) MEMFENCE(); uA = up4[(i0 + 32 + r) * (WW / 4) + col4]; MEMFENCE();
    STAGE(uB, 1) MEMFENCE(); uB = up4[(i0 + 48 + r) * (WW / 4) + col4]; MEMFENCE();
    STAGE(uA, 2) MEMFENCE(); uA = up4[(i0 + 64 + r) * (WW / 4) + col4]; MEMFENCE();
    STAGE(uB, 3) MEMFENCE(); uB = up4[(i0 + 80 + r) * (WW / 4) + col4]; MEMFENCE();
    STAGE(uA, 4) MEMFENCE(); uA = up4[(i0 + 96 + r) * (WW / 4) + col4]; MEMFENCE();
    STAGE(uB, 5) MEMFENCE(); uB = up4[(i0 + 112 + r) * (WW / 4) + col4]; MEMFENCE();

    // issue this unit's loss-window loads (one side); land under stages 6,7
    const float* lr = ihalf ? right : left;
    const int row0 = lane / NV4,       c40 = lane - row0 * NV4;          // e = lane
    const int row1 = (lane + 64) / NV4, c41 = (lane + 64) - row1 * NV4;  // e+64
    const int row2 = (lane + 128) / NV4, c42 = (lane + 128) - row2 * NV4;
    const int row3 = (lane + 192) / NV4, c43 = (lane + 192) - row3 * NV4;
    const size_t wbase = (size_t)k * (HH * WW) + (size_t)j0 * WW + BIN0;
    f32x4 w0 = *(const f32x4*)(lr + wbase + (size_t)row0 * WW + c40 * 4);
    f32x4 w1 = *(const f32x4*)(lr + wbase + (size_t)row1 * WW + c41 * 4);
    f32x4 w2 = *(const f32x4*)(lr + wbase + (size_t)row2 * WW + c42 * 4);
    f32x4 w3 = {0.f, 0.f, 0.f, 0.f};
    if (lane < 32) w3 = *(const f32x4*)(lr + wbase + (size_t)row3 * WW + c43 * 4);
    MEMFENCE();

    STAGE(uA, 6)
    STAGE(uB, 7)
    #undef STAGE

    // own-wave DS ordering: atomics retire before reads (in-order LDS);
    // fence keeps the compiler from reordering the reads above the atomics.
    asm volatile("s_waitcnt lgkmcnt(0)" ::: "memory");

    // ---- loss phase: own bins (LDS) vs prefetched window (regs) ----
    double lsum = 0.0;
    #define LOSS_E(ROW, C4, WV, GUARD)                                        \
    if (GUARD) {                                                              \
        const int4 a = *(const int4*)(mybins + (ROW) * BINP + (C4) * 4);      \
        const int* ai = (const int*)&a;                                       \
        _Pragma("unroll")                                                     \
        for (int c = 0; c < 4; ++c) {                                         \
            const float fl = __int_as_float(ai[c]);                           \
            if (fl != 0.0f) {                                                 \
                const float d = fabsf(__fsub_rn(fl, (WV)[c]));                \
                if (d < 0.2f) lsum += (double)d;                              \
            }                                                                 \
        }                                                                     \
    }
    LOSS_E(row0, c40, w0, true)
    LOSS_E(row1, c41, w1, true)
    LOSS_E(row2, c42, w2, true)
    LOSS_E(row3, c43, w3, (lane < 32))
    #undef LOSS_E

    // wave-only reduction; no cross-wave traffic
    #pragma unroll
    for (int off = 32; off > 0; off >>= 1)
        lsum += __shfl_down(lsum, off, 64);
    if (lane == 0) partial[gid] = lsum;   // written every call
}

__global__ __launch_bounds__(NTHREADS)
void finalize_kernel(const double* __restrict__ partial, float* __restrict__ out) {
    double s = 0.0;
    for (int e = threadIdx.x; e < NUNITS; e += NTHREADS) s += partial[e];
    #pragma unroll
    for (int off = 32; off > 0; off >>= 1)
        s += __shfl_down(s, off, 64);
    __shared__ double sh[NTHREADS / 64];
    if ((threadIdx.x & 63) == 0) sh[threadIdx.x >> 6] = s;
    __syncthreads();
    if (threadIdx.x == 0) {
        double t = 0.0;
        #pragma unroll
        for (int w2 = 0; w2 < NTHREADS / 64; ++w2) t += sh[w2];
        out[0] = (float)(t / NTOT);
    }
}

extern "C" void kernel_launch(void* const* d_in, const int* in_sizes, int n_in,
                              void* d_out, int out_size, void* d_ws, size_t ws_size,
                              hipStream_t stream) {
    const float* up    = (const float*)d_in[0];
    const float* left  = (const float*)d_in[1];
    const float* right = (const float*)d_in[2];
    float* out = (float*)d_out;
    double* partial = (double*)d_ws;   // NUNITS doubles = 32 KB

    scatter_loss_kernel<<<dim3(NBLOCKS), dim3(NTHREADS), 0, stream>>>(
        up, left, right, partial);
    finalize_kernel<<<dim3(1), dim3(NTHREADS), 0, stream>>>(partial, out);
}

// Round 14
// 18.821 us; speedup vs baseline: 1.4057x; 1.0176x over previous
//
#include <hip/hip_runtime.h>

typedef float f32x4 __attribute__((ext_vector_type(4)));

#define BB 128
#define HH 256
#define WW 256
#define NTHREADS 512
#define NBLOCKS (BB * 4)          // (k, side, jhalf): 512 = 2 blocks/CU
#define NTOT ((double)((size_t)BB * WW * WW))

// Reachable bins for u in [0.0235, 1): rint(50u+110) in [111,160].
// 56-wide window [108,164); outside provably zero.
#define BIN0 108
#define BINW 56
#define BINP 60                   // bins row stride: 240B (16B-aligned, odd/4 -> 2-class bank spread)
#define SV4  14                   // stage: 14 f32x4 per row (56 floats, linear for DMA)
#define NJ   128                  // local j columns per block
#define NW4  (NJ * SV4)           // 1792 window f32x4
#define NCH  (NW4 / 64)           // 28 DMA chunks

#define MEMFENCE() asm volatile("" ::: "memory")

__global__ __launch_bounds__(NTHREADS, 4)
void scatter_loss_kernel(const float* __restrict__ up,
                         const float* __restrict__ left,
                         const float* __restrict__ right,
                         double* __restrict__ partial) {
    // Block owns (k, i-half, j-half): up reads are LINEAR (wave = 16
    // consecutive rows, 1KB contiguous per load instr) -> DRAM-row friendly.
    // bins[j][bw] per-lane-distinct j -> no same-address atomic collisions.
    __shared__ __align__(16) int   bins[NJ][BINP];   // 30720 B
    __shared__ __align__(16) float stage[NJ][SV4*4]; // 28672 B, DMA-linear

    const int bid  = blockIdx.x;
    const int jh   = bid & 1;
    const int side = (bid >> 1) & 1;       // 0: i in [0,128) left; 1: [128,256) right
    const int k    = bid >> 2;
    const int tid  = threadIdx.x;
    const int w    = tid >> 6;
    const int lane = tid & 63;

    const int i0    = side << 7;
    const int lhalf = lane >> 5;           // which row of the 2-row load
    const int jl4   = lane & 31;           // f32x4 within the 128-col half
    // wave w streams rows i0 + w*16 .. +15; stage T = rows (+2T, +2T+1)
    const float* upb = up + (size_t)k * (HH * WW)
                     + (size_t)(i0 + w * 16 + lhalf) * WW
                     + (size_t)jh * NJ + jl4 * 4;
    #define LD(T) (*(const f32x4*)(upb + (T) * 2 * WW))

    // ---- depth-3 ring: issue stages 0,1,2 ----
    f32x4 uA = LD(0);
    f32x4 uB = LD(1);
    f32x4 uC = LD(2);

    // zero bins: 128*60 = 7680 ints = 1920 int4
    int4* b4 = (int4*)&bins[0][0];
    const int4 z4 = {0, 0, 0, 0};
    b4[tid] = z4; b4[tid + 512] = z4; b4[tid + 1024] = z4;
    if (tid < 384) b4[tid + 1536] = z4;

    asm volatile("s_waitcnt lgkmcnt(0)" ::: "memory");
    __builtin_amdgcn_s_barrier();

    int* binsp = &bins[0][0];
    const int jrow = jl4 * 4;              // local j for c=0
    // i==128 (side1,w=0,T=0,lhalf=0): ad=0 -> v=0 -> atomicMax no-op = ref.
    #define SCATTER(UV, T)                                                    \
    {                                                                         \
        asm volatile("" : "+v"(UV));  /* counted vmcnt wait for UV */         \
        const int i = i0 + w * 16 + 2 * (T) + lhalf;                          \
        const int ad = side ? (i - 128) : (128 - i);                          \
        const float v = __fdiv_rn((float)ad, 60.0f);                          \
        const int vbits = __float_as_int(v);                                  \
        _Pragma("unroll")                                                     \
        for (int c = 0; c < 4; ++c) {                                         \
            const float uval = (UV)[c];                                       \
            if (uval >= 0.0235f) {                                            \
                /* clip(rint(u*50+110),0,255); no FMA contraction; */         \
                /* rintf = round-half-even = np.round.             */         \
                const float t2 = __fadd_rn(__fmul_rn(uval, 50.0f), 110.0f);   \
                int bin = (int)rintf(t2);                                     \
                int bw = min(max(bin - BIN0, 0), BINW - 1);                   \
                atomicMax(binsp + (jrow + c) * BINP + bw, vbits);             \
            }                                                                 \
        }                                                                     \
    }

    // window DMA: chunk ch -> stage bytes [ch*1024, +1024); src strided rows
    const float* lr = side ? right : left;
    const size_t lrbase = (size_t)k * (HH * WW) + (size_t)jh * NJ * WW + BIN0;
    char* sb = (char*)&stage[0][0];
    #define DMAW(CH)                                                          \
    {                                                                         \
        const int e = (CH) * 64 + lane;                                       \
        const int row = e / SV4, c4 = e - row * SV4;                          \
        __builtin_amdgcn_global_load_lds(                                     \
            (const __attribute__((address_space(1))) void*)                   \
                (lr + lrbase + (size_t)row * WW + c4 * 4),                    \
            (__attribute__((address_space(3))) void*)(sb + (CH) * 1024),      \
            16, 0, 0);                                                        \
    }

    // ---- paced linear stream: consume stage T, issue T+3 ----
    SCATTER(uA, 0) MEMFENCE(); f32x4 uD = LD(3); MEMFENCE();
    SCATTER(uB, 1) MEMFENCE();
    uA = LD(4);
    DMAW(w) DMAW(w + 8) DMAW(w + 16)
    if (w < NCH - 24) DMAW(w + 24)
    MEMFENCE();
    SCATTER(uC, 2) MEMFENCE(); uB = LD(5); MEMFENCE();
    SCATTER(uD, 3) MEMFENCE(); uC = LD(6); MEMFENCE();
    SCATTER(uA, 4) MEMFENCE(); uD = LD(7); MEMFENCE();
    SCATTER(uB, 5)
    SCATTER(uC, 6)
    SCATTER(uD, 7)
    #undef SCATTER
    #undef LD
    #undef DMAW

    // full sync: drains vmcnt(0) (DMA landed) + lgkm (atomics done)
    __syncthreads();

    // ---- loss phase: bins vs staged window, all LDS ----
    float lsum = 0.0f;                     // <=16 adds of <0.2: error ~1e-6
    const int4*  bi4 = (const int4*)&bins[0][0];
    const f32x4* st4 = (const f32x4*)&stage[0][0];
    #define LOSS_I(IDX)                                                       \
    {                                                                         \
        const int row = (IDX) / SV4, c4 = (IDX) - row * SV4;                  \
        const int4 a = bi4[row * (BINP / 4) + c4];                            \
        const f32x4 wv = st4[IDX];                                            \
        const int* ai = (const int*)&a;                                       \
        _Pragma("unroll")                                                     \
        for (int c = 0; c < 4; ++c) {                                         \
            const float fl = __int_as_float(ai[c]);                           \
            if (fl != 0.0f) {                                                 \
                const float d = fabsf(__fsub_rn(fl, wv[c]));                  \
                if (d < 0.2f) lsum += d;                                      \
            }                                                                 \
        }                                                                     \
    }
    LOSS_I(tid) LOSS_I(tid + 512) LOSS_I(tid + 1024)
    if (tid < 256) LOSS_I(tid + 1536)
    #undef LOSS_I

    // wave reduce in f64, cross-wave via LDS
    double dsum = (double)lsum;
    #pragma unroll
    for (int off = 32; off > 0; off >>= 1)
        dsum += __shfl_down(dsum, off, 64);
    __shared__ double wsum[NTHREADS / 64];
    if (lane == 0) wsum[w] = dsum;
    __syncthreads();
    if (tid == 0) {
        double t = 0.0;
        #pragma unroll
        for (int w2 = 0; w2 < NTHREADS / 64; ++w2) t += wsum[w2];
        partial[bid] = t;   // plain store, written every call
    }
}

__global__ __launch_bounds__(256)
void finalize_kernel(const double* __restrict__ partial, float* __restrict__ out) {
    double s = 0.0;
    for (int e = threadIdx.x; e < NBLOCKS; e += 256) s += partial[e];
    #pragma unroll
    for (int off = 32; off > 0; off >>= 1)
        s += __shfl_down(s, off, 64);
    __shared__ double sh[4];
    if ((threadIdx.x & 63) == 0) sh[threadIdx.x >> 6] = s;
    __syncthreads();
    if (threadIdx.x == 0) {
        double t = 0.0;
        #pragma unroll
        for (int w2 = 0; w2 < 4; ++w2) t += sh[w2];
        out[0] = (float)(t / NTOT);
    }
}

extern "C" void kernel_launch(void* const* d_in, const int* in_sizes, int n_in,
                              void* d_out, int out_size, void* d_ws, size_t ws_size,
                              hipStream_t stream) {
    const float* up    = (const float*)d_in[0];
    const float* left  = (const float*)d_in[1];
    const float* right = (const float*)d_in[2];
    float* out = (float*)d_out;
    double* partial = (double*)d_ws;   // NBLOCKS doubles = 4 KB

    scatter_loss_kernel<<<dim3(NBLOCKS), dim3(NTHREADS), 0, stream>>>(
        up, left, right, partial);
    finalize_kernel<<<dim3(1), dim3(256), 0, stream>>>(partial, out);
}

// Round 15
// 18.178 us; speedup vs baseline: 1.4555x; 1.0354x over previous
//
#include <hip/hip_runtime.h>

typedef float f32x4 __attribute__((ext_vector_type(4)));

#define BB 128
#define HH 256
#define WW 256
#define TILE_J 16
#define NTHREADS 256
#define JTILES (WW / TILE_J)      // 16
#define NBLOCKS (BB * JTILES)     // 2048
#define NTOT ((double)((size_t)BB * WW * WW))

// Reachable bins for u in [0.0235, 1): rint(50u+110) in [111,160].
// 56-wide, 16B-aligned window [108,164); outside is provably zero.
#define BIN0 108
#define BINW 56
#define BINP 56                   // 224 B rows, 16B-aligned
#define NV4  (BINW / 4)           // 14 float4 per row
#define NLOSS (TILE_J * NV4)      // 224 float4s per side per block

// Full compiler memory fence: loads cannot be hoisted/sunk across.
#define MEMFENCE() asm volatile("" ::: "memory")

// Non-temporal load: nt CPol bit -> stream past L2/L3 allocation (no fill
// transit; the byte crosses the fabric once, HBM->CU).
#define NTLOAD(P) __builtin_nontemporal_load(P)

__global__ __launch_bounds__(NTHREADS, 8)
void scatter_loss_kernel(const float* __restrict__ up,
                         const float* __restrict__ left,
                         const float* __restrict__ right,
                         double* __restrict__ partial) {
    __shared__ __align__(16) int   bins[2][TILE_J][BINP];   // 7168 B, float bits
    __shared__ __align__(16) float stage[2][TILE_J][BINP];  // 7168 B, l/r windows

    const int bid = blockIdx.x;
    const int k  = bid & 127;        // batch; all 16 j-tiles of k on one XCD
    const int jt = bid >> 7;         // 0..15
    const int j0 = jt * TILE_J;
    const int tid = threadIdx.x;

    const int q = tid & 3;           // float4 within the 16-col row
    const int r = tid >> 2;          // 0..63
    const f32x4* up4 = (const f32x4*)(up + (size_t)k * (HH * WW));
    const int col4 = (j0 >> 2) + q;

    // ---- depth-2 pipeline: issue u0,u1 only (non-temporal) ----
    f32x4 u0 = NTLOAD(&up4[(r +   0) * (WW / 4) + col4]);
    f32x4 u1 = NTLOAD(&up4[(r +  64) * (WW / 4) + col4]);

    // zero bins: 2*16*56 = 1792 ints, 7 per thread (overlaps u0/u1 latency)
    #pragma unroll
    for (int e = tid; e < 2 * TILE_J * BINP; e += NTHREADS)
        (&bins[0][0][0])[e] = 0;

    MEMFENCE();                       // u2 issue stays HERE (not hoisted)
    f32x4 u2 = NTLOAD(&up4[(r + 128) * (WW / 4) + col4]);
    MEMFENCE();

    // barrier 1: LDS-only drain + raw barrier (bins zeroed); VMEM in flight.
    asm volatile("s_waitcnt lgkmcnt(0)" ::: "memory");
    __builtin_amdgcn_s_barrier();

    #define SCATTER_S(UV, S)                                                  \
    {                                                                         \
        const int i = r + 64 * (S);                                           \
        const int sidesel = (i > 128) ? 1 : 0;                                \
        const int ad = sidesel ? (i - 128) : (128 - i); /* i==128 -> no-op */ \
        const float v = __fdiv_rn((float)ad, 60.0f);                          \
        const int vbits = __float_as_int(v);                                  \
        int* srow = &bins[sidesel][q * 4][0];                                 \
        _Pragma("unroll")                                                     \
        for (int c = 0; c < 4; ++c) {                                         \
            const float uval = (UV)[c];                                       \
            if (uval >= 0.0235f) {                                            \
                /* clip(rint(u*50+110),0,255); no FMA contraction; */         \
                /* rintf = round-half-even = np.round.             */         \
                const float t = __fadd_rn(__fmul_rn(uval, 50.0f), 110.0f);    \
                int bin = (int)rintf(t);                                      \
                int bw = min(max(bin - BIN0, 0), BINW - 1);                   \
                atomicMax(srow + c * BINP + bw, vbits);                       \
            }                                                                 \
        }                                                                     \
    }

    // ---- stage 0: wait u0, scatter; consumption paces issue ----
    asm volatile("" : "+v"(u0));      // forces counted vmcnt wait for u0 only
    SCATTER_S(u0, 0)

    // issue u3 + window DMAs now (arrive during s1..s3 / loss barrier)
    MEMFENCE();
    f32x4 u3 = NTLOAD(&up4[(r + 192) * (WW / 4) + col4]);
    const int lrow = tid / NV4;
    const int lc4  = tid - lrow * NV4;
    if (tid < NLOSS) {
        const size_t goff = (size_t)k * (HH * WW) + (size_t)(j0 + lrow) * WW
                          + BIN0 + (size_t)lc4 * 4;
        const int wv = tid >> 6;
        char* sbase = (char*)(&stage[0][0][0]);
        __builtin_amdgcn_global_load_lds(
            (const __attribute__((address_space(1))) void*)(left + goff),
            (__attribute__((address_space(3))) void*)(sbase + wv * 1024),
            16, 0, 0);
        __builtin_amdgcn_global_load_lds(
            (const __attribute__((address_space(1))) void*)(right + goff),
            (__attribute__((address_space(3))) void*)(sbase + 3584 + wv * 1024),
            16, 0, 0);
    }
    MEMFENCE();

    // ---- stage 1..3 ----
    asm volatile("" : "+v"(u1));
    SCATTER_S(u1, 1)
    asm volatile("" : "+v"(u2));
    SCATTER_S(u2, 2)
    asm volatile("" : "+v"(u3));
    SCATTER_S(u3, 3)
    #undef SCATTER_S

    // barrier 2: full __syncthreads -> drains vmcnt(0); staged left/right
    // windows guaranteed landed in LDS.
    __syncthreads();

    // ---- loss phase: everything from LDS, no global stalls ----
    double lsum = 0.0;
    if (tid < NLOSS) {
        const int4 a = *(const int4*)&bins[0][lrow][lc4 * 4];
        const int4 b = *(const int4*)&bins[1][lrow][lc4 * 4];
        const float4 lv = *(const float4*)&stage[0][lrow][lc4 * 4];
        const float4 rv = *(const float4*)&stage[1][lrow][lc4 * 4];
        const int* ai = (const int*)&a;
        const int* bi = (const int*)&b;
        const float* lf = (const float*)&lv;
        const float* rf = (const float*)&rv;
        #pragma unroll
        for (int c = 0; c < 4; ++c) {
            const float fl = __int_as_float(ai[c]);
            const float fr = __int_as_float(bi[c]);
            if (fl != 0.0f) {
                const float d = fabsf(__fsub_rn(fl, lf[c]));
                if (d < 0.2f) lsum += (double)d;
            }
            if (fr != 0.0f) {
                const float d = fabsf(__fsub_rn(fr, rf[c]));
                if (d < 0.2f) lsum += (double)d;
            }
        }
    }

    // block reduction (double): wave shfl then cross-wave via LDS
    #pragma unroll
    for (int off = 32; off > 0; off >>= 1)
        lsum += __shfl_down(lsum, off, 64);
    __shared__ double wsum[NTHREADS / 64];
    if ((tid & 63) == 0) wsum[tid >> 6] = lsum;
    __syncthreads();
    if (tid == 0) {
        double t = 0.0;
        #pragma unroll
        for (int w2 = 0; w2 < NTHREADS / 64; ++w2) t += wsum[w2];
        partial[bid] = t;   // plain store, written every call
    }
}

__global__ __launch_bounds__(NTHREADS)
void finalize_kernel(const double* __restrict__ partial, float* __restrict__ out) {
    double s = 0.0;
    for (int e = threadIdx.x; e < NBLOCKS; e += NTHREADS) s += partial[e];
    #pragma unroll
    for (int off = 32; off > 0; off >>= 1)
        s += __shfl_down(s, off, 64);
    __shared__ double sh[NTHREADS / 64];
    if ((threadIdx.x & 63) == 0) sh[threadIdx.x >> 6] = s;
    __syncthreads();
    if (threadIdx.x == 0) {
        double t = 0.0;
        #pragma unroll
        for (int w2 = 0; w2 < NTHREADS / 64; ++w2) t += sh[w2];
        out[0] = (float)(t / NTOT);
    }
}

extern "C" void kernel_launch(void* const* d_in, const int* in_sizes, int n_in,
                              void* d_out, int out_size, void* d_ws, size_t ws_size,
                              hipStream_t stream) {
    const float* up    = (const float*)d_in[0];
    const float* left  = (const float*)d_in[1];
    const float* right = (const float*)d_in[2];
    float* out = (float*)d_out;
    double* partial = (double*)d_ws;   // NBLOCKS doubles = 16 KB

    scatter_loss_kernel<<<dim3(NBLOCKS), dim3(NTHREADS), 0, stream>>>(
        up, left, right, partial);
    finalize_kernel<<<dim3(1), dim3(NTHREADS), 0, stream>>>(partial, out);
}

// Round 16
// 17.463 us; speedup vs baseline: 1.5150x; 1.0409x over previous
//
#include <hip/hip_runtime.h>

typedef float f32x4 __attribute__((ext_vector_type(4)));

#define BB 128
#define HH 256
#define WW 256
#define TILE_J 16
#define NTHREADS 256
#define JTILES (WW / TILE_J)      // 16
#define NBLOCKS (BB * JTILES)     // 2048
#define NTOT ((double)((size_t)BB * WW * WW))

// Reachable bins for u in [0.0235, 1): rint(50u+110) in [111,160].
// 56-wide, 16B-aligned window [108,164); outside is provably zero.
#define BIN0 108
#define BINW 56
#define BINP 56                   // 224 B rows, 16B-aligned
#define NV4  (BINW / 4)           // 14 float4 per row
#define NLOSS (TILE_J * NV4)      // 224 float4s per side per block

// Full compiler memory fence: loads cannot be hoisted/sunk across.
#define MEMFENCE() asm volatile("" ::: "memory")

__global__ __launch_bounds__(NTHREADS, 8)
void scatter_loss_kernel(const float* __restrict__ up,
                         const float* __restrict__ left,
                         const float* __restrict__ right,
                         double* __restrict__ partial) {
    __shared__ __align__(16) int   bins[2][TILE_J][BINP];   // 7168 B, float bits
    __shared__ __align__(16) float stage[2][TILE_J][BINP];  // 7168 B, l/r windows

    const int bid = blockIdx.x;
    const int k  = bid & 127;        // batch; all 16 j-tiles of k on one XCD
    const int jt = bid >> 7;         // 0..15
    const int j0 = jt * TILE_J;
    const int tid = threadIdx.x;

    const int q = tid & 3;           // float4 within the 16-col row
    const int r = tid >> 2;          // 0..63
    const f32x4* up4 = (const f32x4*)(up + (size_t)k * (HH * WW));
    const int col4 = (j0 >> 2) + q;

    // ---- depth-2 pipeline: issue u0,u1 only ----
    f32x4 u0 = up4[(r +   0) * (WW / 4) + col4];
    f32x4 u1 = up4[(r +  64) * (WW / 4) + col4];

    // zero bins: 2*16*56 = 1792 ints, 7 per thread (overlaps u0/u1 latency)
    #pragma unroll
    for (int e = tid; e < 2 * TILE_J * BINP; e += NTHREADS)
        (&bins[0][0][0])[e] = 0;

    MEMFENCE();                       // u2 issue stays HERE (not hoisted)
    f32x4 u2 = up4[(r + 128) * (WW / 4) + col4];
    MEMFENCE();

    // barrier 1: LDS-only drain + raw barrier (bins zeroed); VMEM in flight.
    asm volatile("s_waitcnt lgkmcnt(0)" ::: "memory");
    __builtin_amdgcn_s_barrier();

    #define SCATTER_S(UV, S)                                                  \
    {                                                                         \
        const int i = r + 64 * (S);                                           \
        const int sidesel = (i > 128) ? 1 : 0;                                \
        const int ad = sidesel ? (i - 128) : (128 - i); /* i==128 -> no-op */ \
        const float v = __fdiv_rn((float)ad, 60.0f);                          \
        const int vbits = __float_as_int(v);                                  \
        int* srow = &bins[sidesel][q * 4][0];                                 \
        _Pragma("unroll")                                                     \
        for (int c = 0; c < 4; ++c) {                                         \
            const float uval = (UV)[c];                                       \
            if (uval >= 0.0235f) {                                            \
                /* clip(rint(u*50+110),0,255); no FMA contraction; */         \
                /* rintf = round-half-even = np.round.             */         \
                const float t = __fadd_rn(__fmul_rn(uval, 50.0f), 110.0f);    \
                int bin = (int)rintf(t);                                      \
                int bw = min(max(bin - BIN0, 0), BINW - 1);                   \
                atomicMax(srow + c * BINP + bw, vbits);                       \
            }                                                                 \
        }                                                                     \
    }

    // ---- stage 0: wait u0, scatter; consumption paces issue ----
    asm volatile("" : "+v"(u0));      // forces counted vmcnt wait for u0 only
    SCATTER_S(u0, 0)

    // issue u3 + window DMAs now (arrive during s1..s3 / loss barrier)
    MEMFENCE();
    f32x4 u3 = up4[(r + 192) * (WW / 4) + col4];
    const int lrow = tid / NV4;
    const int lc4  = tid - lrow * NV4;
    if (tid < NLOSS) {
        const size_t goff = (size_t)k * (HH * WW) + (size_t)(j0 + lrow) * WW
                          + BIN0 + (size_t)lc4 * 4;
        const int wv = tid >> 6;
        char* sbase = (char*)(&stage[0][0][0]);
        __builtin_amdgcn_global_load_lds(
            (const __attribute__((address_space(1))) void*)(left + goff),
            (__attribute__((address_space(3))) void*)(sbase + wv * 1024),
            16, 0, 0);
        __builtin_amdgcn_global_load_lds(
            (const __attribute__((address_space(1))) void*)(right + goff),
            (__attribute__((address_space(3))) void*)(sbase + 3584 + wv * 1024),
            16, 0, 0);
    }
    MEMFENCE();

    // ---- stage 1..3 ----
    asm volatile("" : "+v"(u1));
    SCATTER_S(u1, 1)
    asm volatile("" : "+v"(u2));
    SCATTER_S(u2, 2)
    asm volatile("" : "+v"(u3));
    SCATTER_S(u3, 3)
    #undef SCATTER_S

    // barrier 2: full __syncthreads -> drains vmcnt(0); staged left/right
    // windows guaranteed landed in LDS.
    __syncthreads();

    // ---- loss phase: everything from LDS, no global stalls ----
    double lsum = 0.0;
    if (tid < NLOSS) {
        const int4 a = *(const int4*)&bins[0][lrow][lc4 * 4];
        const int4 b = *(const int4*)&bins[1][lrow][lc4 * 4];
        const float4 lv = *(const float4*)&stage[0][lrow][lc4 * 4];
        const float4 rv = *(const float4*)&stage[1][lrow][lc4 * 4];
        const int* ai = (const int*)&a;
        const int* bi = (const int*)&b;
        const float* lf = (const float*)&lv;
        const float* rf = (const float*)&rv;
        #pragma unroll
        for (int c = 0; c < 4; ++c) {
            const float fl = __int_as_float(ai[c]);
            const float fr = __int_as_float(bi[c]);
            if (fl != 0.0f) {
                const float d = fabsf(__fsub_rn(fl, lf[c]));
                if (d < 0.2f) lsum += (double)d;
            }
            if (fr != 0.0f) {
                const float d = fabsf(__fsub_rn(fr, rf[c]));
                if (d < 0.2f) lsum += (double)d;
            }
        }
    }

    // block reduction (double): wave shfl then cross-wave via LDS
    #pragma unroll
    for (int off = 32; off > 0; off >>= 1)
        lsum += __shfl_down(lsum, off, 64);
    __shared__ double wsum[NTHREADS / 64];
    if ((tid & 63) == 0) wsum[tid >> 6] = lsum;
    __syncthreads();
    if (tid == 0) {
        double t = 0.0;
        #pragma unroll
        for (int w2 = 0; w2 < NTHREADS / 64; ++w2) t += wsum[w2];
        partial[bid] = t;   // plain store, written every call
    }
}

__global__ __launch_bounds__(NTHREADS)
void finalize_kernel(const double* __restrict__ partial, float* __restrict__ out) {
    double s = 0.0;
    for (int e = threadIdx.x; e < NBLOCKS; e += NTHREADS) s += partial[e];
    #pragma unroll
    for (int off = 32; off > 0; off >>= 1)
        s += __shfl_down(s, off, 64);
    __shared__ double sh[NTHREADS / 64];
    if ((threadIdx.x & 63) == 0) sh[threadIdx.x >> 6] = s;
    __syncthreads();
    if (threadIdx.x == 0) {
        double t = 0.0;
        #pragma unroll
        for (int w2 = 0; w2 < NTHREADS / 64; ++w2) t += sh[w2];
        out[0] = (float)(t / NTOT);
    }
}

extern "C" void kernel_launch(void* const* d_in, const int* in_sizes, int n_in,
                              void* d_out, int out_size, void* d_ws, size_t ws_size,
                              hipStream_t stream) {
    const float* up    = (const float*)d_in[0];
    const float* left  = (const float*)d_in[1];
    const float* right = (const float*)d_in[2];
    float* out = (float*)d_out;
    double* partial = (double*)d_ws;   // NBLOCKS doubles = 16 KB

    scatter_loss_kernel<<<dim3(NBLOCKS), dim3(NTHREADS), 0, stream>>>(
        up, left, right, partial);
    finalize_kernel<<<dim3(1), dim3(NTHREADS), 0, stream>>>(partial, out);
}